// Round 1
// baseline (1166.182 us; speedup 1.0000x reference)
//
#include <hip/hip_runtime.h>

// D-MPNN forward for MI355X (gfx950).
// Pipeline (all bf16 intermediates, fp32 accum):
//  padcvt f_bonds->fb16[NB][160], f_atoms->fa16[NA][160]
//  transpose/pad weights to Wt[n][k] bf16
//  K1 : inp = fb16 @ W_i            (MFMA 32x32x16, bf16 out)
//  iter1: amsg = sum_j relu(inp[a2b]) ; msgA = relu(inp + (amsg[b2a]-relu(inp[b2revb]))@W_h)
//  iter2: amsg = sum_j msgA[a2b]      ; msgB = relu(inp + (amsg[b2a]-msgA[b2revb])@W_h)
//  final: amsg = sum_j msgB[a2b] ; pf = fa16@W_o[:133] ; ah = relu(pf + amsg@W_o[133:] + b_o)
//  out = mean over 20 atoms/mol of ah[1:]

#define DI __device__ __forceinline__

typedef __bf16 bf16x8 __attribute__((ext_vector_type(8)));
typedef float f32x8 __attribute__((ext_vector_type(8)));
typedef float f32x16 __attribute__((ext_vector_type(16)));
typedef unsigned short u16x8 __attribute__((ext_vector_type(8)));

static constexpr int cNA = 120001;
static constexpr int cNB = 260001;
static constexpr int cAF = 133;
static constexpr int cBF = 147;
static constexpr int KP_F = 160;   // padded feature K (both 147->160 and 133->160)

DI bf16x8 ldbf8(const unsigned short* p) {
  return __builtin_bit_cast(bf16x8, *reinterpret_cast<const u16x8*>(p));
}
DI void stbf8(unsigned short* p, bf16x8 v) {
  *reinterpret_cast<u16x8*>(p) = __builtin_bit_cast(u16x8, v);
}
DI f32x8 up8(bf16x8 v) { return __builtin_convertvector(v, f32x8); }
DI bf16x8 dn8(f32x8 v) { return __builtin_convertvector(v, bf16x8); }
DI float bfh2f(unsigned short h) { return __builtin_bit_cast(float, (unsigned)h << 16); }
DI unsigned short f2bfh(float f) {
  __bf16 b = (__bf16)f;
  return __builtin_bit_cast(unsigned short, b);
}

// ---------------- pre-convert kernels ----------------
__global__ void k_padcvt(const float* __restrict__ in, unsigned short* __restrict__ out,
                         int nrows, int kin, int kpad) {
  long long total = (long long)nrows * kpad;
  long long i = (long long)blockIdx.x * blockDim.x + threadIdx.x;
  if (i >= total) return;
  int row = (int)(i / kpad);
  int k = (int)(i - (long long)row * kpad);
  float v = (k < kin) ? in[(long long)row * kin + k] : 0.f;
  out[i] = f2bfh(v);
}

// out[n][k] = W[k+rowoff][n], zero-padded past K
__global__ void k_transw(const float* __restrict__ W, unsigned short* __restrict__ out,
                         int K, int kpad, int rowoff) {
  int i = blockIdx.x * blockDim.x + threadIdx.x;
  if (i >= 256 * kpad) return;
  int n = i / kpad, k = i - n * kpad;
  float v = (k < K) ? W[(long long)(k + rowoff) * 256 + n] : 0.f;
  out[i] = f2bfh(v);
}

// ---------------- gather-sum over a2b (6 neighbors) ----------------
__global__ __launch_bounds__(256) void k_gathersum(
    const unsigned short* __restrict__ src, const int* __restrict__ a2b,
    unsigned short* __restrict__ out, int relu_flag) {
  int tid = blockIdx.x * 256 + threadIdx.x;
  if (tid >= cNA * 16) return;
  int atom = tid >> 4, ch = tid & 15;            // 16 threads per atom, 16 cols each
  const int* ab = a2b + (long long)atom * 6;
  float acc[16];
#pragma unroll
  for (int e = 0; e < 16; e++) acc[e] = 0.f;
#pragma unroll
  for (int j = 0; j < 6; j++) {
    int b = ab[j];
    const unsigned short* p = src + (long long)b * 256 + ch * 16;
    f32x8 x0 = up8(ldbf8(p));
    f32x8 x1 = up8(ldbf8(p + 8));
    if (relu_flag) {
#pragma unroll
      for (int e = 0; e < 8; e++) { x0[e] = fmaxf(x0[e], 0.f); x1[e] = fmaxf(x1[e], 0.f); }
    }
#pragma unroll
    for (int e = 0; e < 8; e++) { acc[e] += x0[e]; acc[8 + e] += x1[e]; }
  }
  f32x8 lo, hi;
#pragma unroll
  for (int e = 0; e < 8; e++) { lo[e] = acc[e]; hi[e] = acc[8 + e]; }
  unsigned short* q = out + (long long)atom * 256 + ch * 16;
  stbf8(q, dn8(lo));
  stbf8(q + 8, dn8(hi));
}

// ---------------- MFMA GEMM family ----------------
// Each block: 16 waves, 512 rows (32/wave), N=256 (8 col-blocks of 32).
// Full Wt [256][KP] staged in LDS in fragment-contiguous layout:
//   frag (cb,f) at (cb*NF+f)*512 ushorts; lane reads lds + frag*512 + lane*8 (stride-1, no conflicts).
enum { MODE_BF16OUT = 0, MODE_F32OUT = 1, MODE_MSG = 2, MODE_FINAL = 3 };

template <int KP, int MODE, bool RELU_SRC>
__global__ __launch_bounds__(1024) void k_gemm(
    const unsigned short* __restrict__ A,     // direct A [nrows][KP] bf16 (or amsg for MODE_MSG)
    const unsigned short* __restrict__ Msg,   // MODE_MSG: message source [NB][256] bf16
    const int* __restrict__ b2a, const int* __restrict__ b2revb,
    const unsigned short* __restrict__ Wt,    // [256][KP] bf16 (W transposed)
    const unsigned short* __restrict__ Cbf,   // MODE_MSG: inp bf16
    const float* __restrict__ Cf32,           // MODE_FINAL: partial fp32
    const float* __restrict__ bias,           // MODE_FINAL: b_o
    unsigned short* __restrict__ OutBf, float* __restrict__ OutF32, int nrows) {
  constexpr int NF = KP / 16;   // K-frags per col-block
  constexpr int NCB = 8;        // 256/32
  __shared__ unsigned short lds[NCB * NF * 512];

  const int tid = threadIdx.x;
  for (int c = tid; c < NCB * NF * 64; c += 1024) {
    int frag = c >> 6, slot = c & 63;
    int cb = frag / NF, f = frag - cb * NF;
    int col = cb * 32 + (slot & 31);
    int koff = f * 16 + (slot >> 5) * 8;        // ushort units within row
    *reinterpret_cast<u16x8*>(lds + c * 8) =
        *reinterpret_cast<const u16x8*>(Wt + (long long)col * KP + koff);
  }
  __syncthreads();

  const int lane = tid & 63, wid = tid >> 6;
  const int rbase = blockIdx.x * 512 + wid * 32;
  const int rA = rbase + (lane & 31);
  const bool valid = rA < nrows;
  const int rS = valid ? rA : 0;
  const int kg = lane >> 5;  // 0/1: which 8-wide K half of the 16-K fragment

  bf16x8 af[NF];
  if (MODE == MODE_MSG) {
    int ib = b2a[rS];
    int irv = b2revb[rS];
    const unsigned short* pa = A + (long long)ib * 256;
    const unsigned short* pm = Msg + (long long)irv * 256;
#pragma unroll
    for (int f = 0; f < NF; f++) {
      int off = f * 16 + kg * 8;
      f32x8 xa = up8(ldbf8(pa + off));
      f32x8 xm = up8(ldbf8(pm + off));
      if (RELU_SRC) {
#pragma unroll
        for (int e = 0; e < 8; e++) xm[e] = fmaxf(xm[e], 0.f);
      }
      af[f] = dn8(xa - xm);
    }
  } else {
    const unsigned short* pa = A + (long long)rS * KP;
#pragma unroll
    for (int f = 0; f < NF; f++) af[f] = ldbf8(pa + f * 16 + kg * 8);
  }

#pragma unroll 1
  for (int cb = 0; cb < NCB; cb++) {
    f32x16 acc;
#pragma unroll
    for (int q = 0; q < 16; q++) acc[q] = 0.f;
    const unsigned short* lb = lds + cb * NF * 512 + lane * 8;
#pragma unroll
    for (int f = 0; f < NF; f++) {
      bf16x8 b = ldbf8(lb + f * 512);
      acc = __builtin_amdgcn_mfma_f32_32x32x16_bf16(af[f], b, acc, 0, 0, 0);
    }
    // epilogue: C/D layout col=lane&31, row=(q&3)+8*(q>>2)+4*(lane>>5)
    int col = cb * 32 + (lane & 31);
    int rb2 = rbase + 4 * kg;
    float bv = (MODE == MODE_FINAL) ? bias[col] : 0.f;
#pragma unroll
    for (int q = 0; q < 16; q++) {
      int row = rb2 + (q & 3) + 8 * (q >> 2);
      if (row >= nrows) continue;
      float v = acc[q];
      long long idx = (long long)row * 256 + col;
      if (MODE == MODE_BF16OUT) {
        OutBf[idx] = f2bfh(v);
      } else if (MODE == MODE_F32OUT) {
        OutF32[idx] = v;
      } else if (MODE == MODE_MSG) {
        v += bfh2f(Cbf[idx]);
        v = fmaxf(v, 0.f);
        OutBf[idx] = f2bfh(v);
      } else {  // MODE_FINAL
        v += Cf32[idx] + bv;
        v = fmaxf(v, 0.f);
        OutF32[idx] = v;
      }
    }
  }
}

// ---------------- molecule mean-pool ----------------
__global__ __launch_bounds__(256) void k_meanpool(const float* __restrict__ ah,
                                                  float* __restrict__ out) {
  int m = blockIdx.x, c = threadIdx.x;
  float s = 0.f;
#pragma unroll
  for (int i = 0; i < 20; i++) s += ah[(long long)(1 + m * 20 + i) * 256 + c];
  out[(long long)m * 256 + c] = s * 0.05f;
}

extern "C" void kernel_launch(void* const* d_in, const int* in_sizes, int n_in,
                              void* d_out, int out_size, void* d_ws, size_t ws_size,
                              hipStream_t stream) {
  const float* f_atoms = (const float*)d_in[0];
  const float* f_bonds = (const float*)d_in[1];
  const int* a2b = (const int*)d_in[2];
  const int* b2a = (const int*)d_in[3];
  const int* b2revb = (const int*)d_in[4];
  const float* W_i = (const float*)d_in[5];
  const float* W_h = (const float*)d_in[6];
  const float* W_o = (const float*)d_in[7];
  const float* b_o = (const float*)d_in[8];
  float* out = (float*)d_out;

  char* ws = (char*)d_ws;
  size_t off = 0;
  auto alloc = [&](size_t b) { size_t o = off; off += (b + 1023) & ~(size_t)1023; return o; };
  size_t o_fb = alloc((size_t)cNB * KP_F * 2);     // fb16; later reused for amsg (61.4MB<=83.2MB)
  size_t o_fa = alloc((size_t)cNA * KP_F * 2);     // fa16
  size_t o_inp = alloc((size_t)cNB * 256 * 2);     // inp bf16
  size_t o_bufA = alloc((size_t)cNB * 256 * 2);    // msgA ; later pf (fp32 NA*256 fits)
  size_t o_bufB = alloc((size_t)cNB * 256 * 2);    // msgB ; later ah (fp32 NA*256 fits)
  size_t o_wti = alloc((size_t)256 * KP_F * 2);
  size_t o_wth = alloc((size_t)256 * 256 * 2);
  size_t o_wo1 = alloc((size_t)256 * KP_F * 2);
  size_t o_wo2 = alloc((size_t)256 * 256 * 2);

  unsigned short* fb16 = (unsigned short*)(ws + o_fb);
  unsigned short* amsg = (unsigned short*)(ws + o_fb);  // overlays fb16 after K1
  unsigned short* fa16 = (unsigned short*)(ws + o_fa);
  unsigned short* inp = (unsigned short*)(ws + o_inp);
  unsigned short* msgA = (unsigned short*)(ws + o_bufA);
  unsigned short* msgB = (unsigned short*)(ws + o_bufB);
  float* pf = (float*)(ws + o_bufA);
  float* ah = (float*)(ws + o_bufB);
  unsigned short* Wti = (unsigned short*)(ws + o_wti);
  unsigned short* Wth = (unsigned short*)(ws + o_wth);
  unsigned short* Wto1 = (unsigned short*)(ws + o_wo1);
  unsigned short* Wto2 = (unsigned short*)(ws + o_wo2);

  dim3 b256(256);
  {
    long long t = (long long)cNB * KP_F;
    k_padcvt<<<(unsigned)((t + 255) / 256), b256, 0, stream>>>(f_bonds, fb16, cNB, cBF, KP_F);
  }
  {
    long long t = (long long)cNA * KP_F;
    k_padcvt<<<(unsigned)((t + 255) / 256), b256, 0, stream>>>(f_atoms, fa16, cNA, cAF, KP_F);
  }
  k_transw<<<(256 * KP_F + 255) / 256, b256, 0, stream>>>(W_i, Wti, cBF, KP_F, 0);
  k_transw<<<(256 * 256 + 255) / 256, b256, 0, stream>>>(W_h, Wth, 256, 256, 0);
  k_transw<<<(256 * KP_F + 255) / 256, b256, 0, stream>>>(W_o, Wto1, cAF, KP_F, 0);
  k_transw<<<(256 * 256 + 255) / 256, b256, 0, stream>>>(W_o, Wto2, 256, 256, cAF);

  const int gB = (cNB + 511) / 512;
  const int gA = (cNA + 511) / 512;
  const int gS = (cNA * 16 + 255) / 256;

  // K1: inp = fb16 @ W_i
  k_gemm<KP_F, MODE_BF16OUT, false><<<gB, 1024, 0, stream>>>(
      fb16, nullptr, nullptr, nullptr, Wti, nullptr, nullptr, nullptr, inp, nullptr, cNB);
  // iter 1
  k_gathersum<<<gS, b256, 0, stream>>>(inp, a2b, amsg, 1);
  k_gemm<256, MODE_MSG, true><<<gB, 1024, 0, stream>>>(
      amsg, inp, b2a, b2revb, Wth, inp, nullptr, nullptr, msgA, nullptr, cNB);
  // iter 2
  k_gathersum<<<gS, b256, 0, stream>>>(msgA, a2b, amsg, 0);
  k_gemm<256, MODE_MSG, false><<<gB, 1024, 0, stream>>>(
      amsg, msgA, b2a, b2revb, Wth, inp, nullptr, nullptr, msgB, nullptr, cNB);
  // readout
  k_gathersum<<<gS, b256, 0, stream>>>(msgB, a2b, amsg, 0);
  k_gemm<KP_F, MODE_F32OUT, false><<<gA, 1024, 0, stream>>>(
      fa16, nullptr, nullptr, nullptr, Wto1, nullptr, nullptr, nullptr, nullptr, pf, cNA);
  k_gemm<256, MODE_FINAL, false><<<gA, 1024, 0, stream>>>(
      amsg, nullptr, nullptr, nullptr, Wto2, nullptr, pf, b_o, nullptr, ah, cNA);
  k_meanpool<<<6000, b256, 0, stream>>>(ah, out);
}

// Round 3
// 1002.788 us; speedup vs baseline: 1.1629x; 1.1629x over previous
//
#include <hip/hip_runtime.h>

// D-MPNN forward for MI355X (gfx950). R3 = R2 with the MODE_FINAL launch-arg fix.

#define DI __device__ __forceinline__

typedef __bf16 bf16x8 __attribute__((ext_vector_type(8)));
typedef float f32x8 __attribute__((ext_vector_type(8)));
typedef float f32x16 __attribute__((ext_vector_type(16)));
typedef unsigned short u16x8 __attribute__((ext_vector_type(8)));

static constexpr int cNA = 120001;
static constexpr int cNB = 260001;
static constexpr int cAF = 133;
static constexpr int cBF = 147;
static constexpr int KP_F = 160;   // padded feature K (both 147->160 and 133->160)

DI bf16x8 ldbf8(const unsigned short* p) {
  return __builtin_bit_cast(bf16x8, *reinterpret_cast<const u16x8*>(p));
}
DI void stbf8(unsigned short* p, bf16x8 v) {
  *reinterpret_cast<u16x8*>(p) = __builtin_bit_cast(u16x8, v);
}
DI f32x8 up8(bf16x8 v) { return __builtin_convertvector(v, f32x8); }
DI f32x8 up8u(u16x8 v) { return up8(__builtin_bit_cast(bf16x8, v)); }
DI bf16x8 dn8(f32x8 v) { return __builtin_convertvector(v, bf16x8); }
DI float bfh2f(unsigned short h) { return __builtin_bit_cast(float, (unsigned)h << 16); }
DI unsigned short f2bfh(float f) {
  __bf16 b = (__bf16)f;
  return __builtin_bit_cast(unsigned short, b);
}

// ---------------- pre-convert kernels ----------------
__global__ void k_padcvt(const float* __restrict__ in, unsigned short* __restrict__ out,
                         int nrows, int kin, int kpad) {
  long long total = (long long)nrows * kpad;
  long long i = (long long)blockIdx.x * blockDim.x + threadIdx.x;
  if (i >= total) return;
  int row = (int)(i / kpad);
  int k = (int)(i - (long long)row * kpad);
  float v = (k < kin) ? in[(long long)row * kin + k] : 0.f;
  out[i] = f2bfh(v);
}

// out[n][k] = W[k+rowoff][n], zero-padded past K
__global__ void k_transw(const float* __restrict__ W, unsigned short* __restrict__ out,
                         int K, int kpad, int rowoff) {
  int i = blockIdx.x * blockDim.x + threadIdx.x;
  if (i >= 256 * kpad) return;
  int n = i / kpad, k = i - n * kpad;
  float v = (k < K) ? W[(long long)(k + rowoff) * 256 + n] : 0.f;
  out[i] = f2bfh(v);
}

// ---------------- gather-sum over a2b (6 neighbors) ----------------
__global__ __launch_bounds__(256) void k_gathersum(
    const unsigned short* __restrict__ src, const int* __restrict__ a2b,
    unsigned short* __restrict__ out, int relu_flag) {
  int tid = blockIdx.x * 256 + threadIdx.x;
  if (tid >= cNA * 16) return;
  int atom = tid >> 4, ch = tid & 15;            // 16 threads per atom, 16 cols each
  const int* ab = a2b + (long long)atom * 6;
  int bidx[6];
#pragma unroll
  for (int j = 0; j < 6; j++) bidx[j] = ab[j];
  u16x8 r0[6], r1[6];
#pragma unroll
  for (int j = 0; j < 6; j++) {
    const unsigned short* p = src + (long long)bidx[j] * 256 + ch * 16;
    r0[j] = *reinterpret_cast<const u16x8*>(p);
    r1[j] = *reinterpret_cast<const u16x8*>(p + 8);
  }
  f32x8 lo = {0.f,0.f,0.f,0.f,0.f,0.f,0.f,0.f}, hi = lo;
#pragma unroll
  for (int j = 0; j < 6; j++) {
    f32x8 x0 = up8u(r0[j]);
    f32x8 x1 = up8u(r1[j]);
    if (relu_flag) {
#pragma unroll
      for (int e = 0; e < 8; e++) { x0[e] = fmaxf(x0[e], 0.f); x1[e] = fmaxf(x1[e], 0.f); }
    }
#pragma unroll
    for (int e = 0; e < 8; e++) { lo[e] += x0[e]; hi[e] += x1[e]; }
  }
  unsigned short* q = out + (long long)atom * 256 + ch * 16;
  stbf8(q, dn8(lo));
  stbf8(q + 8, dn8(hi));
}

// ---------------- MFMA GEMM family ----------------
// Each block: 16 waves, 512 rows (32/wave), N=256 (8 col-blocks of 32).
// Full Wt [256][KP] staged in LDS in fragment-contiguous layout:
//   frag (cb,f) at (cb*NF+f)*512 ushorts; lane reads lds + frag*512 + lane*8 (stride-1, no conflicts).
enum { MODE_BF16OUT = 0, MODE_MSG = 2, MODE_FINAL = 3 };

template <int KP, int MODE, bool RELU_SRC>
__global__ __launch_bounds__(1024) void k_gemm(
    const unsigned short* __restrict__ A,     // direct A [nrows][KP] bf16 (or amsg for MODE_MSG)
    const unsigned short* __restrict__ Msg,   // MODE_MSG: message source [NB][256] bf16
    const int* __restrict__ b2a, const int* __restrict__ b2revb,
    const unsigned short* __restrict__ Wt,    // [256][KP] bf16 (W transposed)
    const unsigned short* __restrict__ Cbf,   // MODE_MSG: inp bf16 ; MODE_FINAL: pf bf16
    const float* __restrict__ bias,           // MODE_FINAL: b_o
    unsigned short* __restrict__ OutBf, int nrows) {
  constexpr int NF = KP / 16;   // K-frags per col-block
  constexpr int NCB = 8;        // 256/32
  __shared__ unsigned short lds[NCB * NF * 512];

  const int tid = threadIdx.x;
  for (int c = tid; c < NCB * NF * 64; c += 1024) {
    int frag = c >> 6, slot = c & 63;
    int cb = frag / NF, f = frag - cb * NF;
    int col = cb * 32 + (slot & 31);
    int koff = f * 16 + (slot >> 5) * 8;        // ushort units within row
    *reinterpret_cast<u16x8*>(lds + c * 8) =
        *reinterpret_cast<const u16x8*>(Wt + (long long)col * KP + koff);
  }
  __syncthreads();

  const int lane = tid & 63, wid = tid >> 6;
  const int rbase = blockIdx.x * 512 + wid * 32;
  const int rA = rbase + (lane & 31);
  const bool valid = rA < nrows;
  const int rS = valid ? rA : 0;
  const int kg = lane >> 5;  // 0/1: which 8-wide K half of the 16-K fragment

  bf16x8 af[NF];
  if (MODE == MODE_MSG) {
    int ib = b2a[rS];
    int irv = b2revb[rS];
    const unsigned short* pa = A + (long long)ib * 256;
    const unsigned short* pm = Msg + (long long)irv * 256;
    u16x8 rawa[NF], rawm[NF];
#pragma unroll
    for (int f = 0; f < NF; f++) {
      int off = f * 16 + kg * 8;
      rawa[f] = *reinterpret_cast<const u16x8*>(pa + off);
      rawm[f] = *reinterpret_cast<const u16x8*>(pm + off);
    }
#pragma unroll
    for (int f = 0; f < NF; f++) {
      f32x8 xa = up8u(rawa[f]);
      f32x8 xm = up8u(rawm[f]);
      if (RELU_SRC) {
#pragma unroll
        for (int e = 0; e < 8; e++) xm[e] = fmaxf(xm[e], 0.f);
      }
      af[f] = dn8(xa - xm);
    }
  } else {
    const unsigned short* pa = A + (long long)rS * KP;
#pragma unroll
    for (int f = 0; f < NF; f++) af[f] = ldbf8(pa + f * 16 + kg * 8);
  }

  // hoist bias loads (MODE_FINAL)
  float bv[NCB];
  if (MODE == MODE_FINAL) {
#pragma unroll
    for (int cb = 0; cb < NCB; cb++) bv[cb] = bias[cb * 32 + (lane & 31)];
  }

#pragma unroll 1
  for (int cb = 0; cb < NCB; cb++) {
    const int col = cb * 32 + (lane & 31);
    const int rb2 = rbase + 4 * kg;

    // (a) batch-issue C loads as raw ushorts; waitcnt sinks past the MFMA chain
    unsigned short craw[16];
    if (MODE == MODE_MSG || MODE == MODE_FINAL) {
#pragma unroll
      for (int q = 0; q < 16; q++) {
        int row = rb2 + (q & 3) + 8 * (q >> 2);
        int rowc = row < nrows ? row : 0;
        craw[q] = Cbf[(long long)rowc * 256 + col];
      }
    }

    // (b) LDS B-frags + MFMA chain
    f32x16 acc;
#pragma unroll
    for (int q = 0; q < 16; q++) acc[q] = 0.f;
    const unsigned short* lb = lds + cb * NF * 512 + lane * 8;
#pragma unroll
    for (int f = 0; f < NF; f++) {
      bf16x8 b = ldbf8(lb + f * 512);
      acc = __builtin_amdgcn_mfma_f32_32x32x16_bf16(af[f], b, acc, 0, 0, 0);
    }

    // (c) merge + store. C/D layout: col=lane&31, row=(q&3)+8*(q>>2)+4*(lane>>5)
#pragma unroll
    for (int q = 0; q < 16; q++) {
      int row = rb2 + (q & 3) + 8 * (q >> 2);
      if (row >= nrows) continue;
      float v = acc[q];
      long long idx = (long long)row * 256 + col;
      if (MODE == MODE_BF16OUT) {
        OutBf[idx] = f2bfh(v);
      } else if (MODE == MODE_MSG) {
        v += bfh2f(craw[q]);
        v = fmaxf(v, 0.f);
        OutBf[idx] = f2bfh(v);
      } else {  // MODE_FINAL
        v += bfh2f(craw[q]) + bv[cb];
        v = fmaxf(v, 0.f);
        OutBf[idx] = f2bfh(v);
      }
    }
  }
}

// ---------------- molecule mean-pool (bf16 in, fp32 out) ----------------
__global__ __launch_bounds__(256) void k_meanpool(const unsigned short* __restrict__ ah,
                                                  float* __restrict__ out) {
  int m = blockIdx.x, c = threadIdx.x;
  unsigned short r[20];
#pragma unroll
  for (int i = 0; i < 20; i++) r[i] = ah[(long long)(1 + m * 20 + i) * 256 + c];
  float s = 0.f;
#pragma unroll
  for (int i = 0; i < 20; i++) s += bfh2f(r[i]);
  out[(long long)m * 256 + c] = s * 0.05f;
}

extern "C" void kernel_launch(void* const* d_in, const int* in_sizes, int n_in,
                              void* d_out, int out_size, void* d_ws, size_t ws_size,
                              hipStream_t stream) {
  const float* f_atoms = (const float*)d_in[0];
  const float* f_bonds = (const float*)d_in[1];
  const int* a2b = (const int*)d_in[2];
  const int* b2a = (const int*)d_in[3];
  const int* b2revb = (const int*)d_in[4];
  const float* W_i = (const float*)d_in[5];
  const float* W_h = (const float*)d_in[6];
  const float* W_o = (const float*)d_in[7];
  const float* b_o = (const float*)d_in[8];
  float* out = (float*)d_out;

  char* ws = (char*)d_ws;
  size_t off = 0;
  auto alloc = [&](size_t b) { size_t o = off; off += (b + 1023) & ~(size_t)1023; return o; };
  size_t o_fb = alloc((size_t)cNB * KP_F * 2);     // fb16; later reused for amsg (61.4MB<=83.2MB)
  size_t o_fa = alloc((size_t)cNA * KP_F * 2);     // fa16
  size_t o_inp = alloc((size_t)cNB * 256 * 2);     // inp bf16
  size_t o_bufA = alloc((size_t)cNB * 256 * 2);    // msgA ; later pf (bf16 NA*256)
  size_t o_bufB = alloc((size_t)cNB * 256 * 2);    // msgB ; later ah (bf16 NA*256)
  size_t o_wti = alloc((size_t)256 * KP_F * 2);
  size_t o_wth = alloc((size_t)256 * 256 * 2);
  size_t o_wo1 = alloc((size_t)256 * KP_F * 2);
  size_t o_wo2 = alloc((size_t)256 * 256 * 2);

  unsigned short* fb16 = (unsigned short*)(ws + o_fb);
  unsigned short* amsg = (unsigned short*)(ws + o_fb);  // overlays fb16 after K1
  unsigned short* fa16 = (unsigned short*)(ws + o_fa);
  unsigned short* inp = (unsigned short*)(ws + o_inp);
  unsigned short* msgA = (unsigned short*)(ws + o_bufA);
  unsigned short* msgB = (unsigned short*)(ws + o_bufB);
  unsigned short* pf = (unsigned short*)(ws + o_bufA);
  unsigned short* ah = (unsigned short*)(ws + o_bufB);
  unsigned short* Wti = (unsigned short*)(ws + o_wti);
  unsigned short* Wth = (unsigned short*)(ws + o_wth);
  unsigned short* Wto1 = (unsigned short*)(ws + o_wo1);
  unsigned short* Wto2 = (unsigned short*)(ws + o_wo2);

  dim3 b256(256);
  {
    long long t = (long long)cNB * KP_F;
    k_padcvt<<<(unsigned)((t + 255) / 256), b256, 0, stream>>>(f_bonds, fb16, cNB, cBF, KP_F);
  }
  {
    long long t = (long long)cNA * KP_F;
    k_padcvt<<<(unsigned)((t + 255) / 256), b256, 0, stream>>>(f_atoms, fa16, cNA, cAF, KP_F);
  }
  k_transw<<<(256 * KP_F + 255) / 256, b256, 0, stream>>>(W_i, Wti, cBF, KP_F, 0);
  k_transw<<<(256 * 256 + 255) / 256, b256, 0, stream>>>(W_h, Wth, 256, 256, 0);
  k_transw<<<(256 * KP_F + 255) / 256, b256, 0, stream>>>(W_o, Wto1, cAF, KP_F, 0);
  k_transw<<<(256 * 256 + 255) / 256, b256, 0, stream>>>(W_o, Wto2, 256, 256, cAF);

  const int gB = (cNB + 511) / 512;
  const int gA = (cNA + 511) / 512;
  const int gS = (cNA * 16 + 255) / 256;

  // K1: inp = fb16 @ W_i
  k_gemm<KP_F, MODE_BF16OUT, false><<<gB, 1024, 0, stream>>>(
      fb16, nullptr, nullptr, nullptr, Wti, nullptr, nullptr, inp, cNB);
  // iter 1
  k_gathersum<<<gS, b256, 0, stream>>>(inp, a2b, amsg, 1);
  k_gemm<256, MODE_MSG, true><<<gB, 1024, 0, stream>>>(
      amsg, inp, b2a, b2revb, Wth, inp, nullptr, msgA, cNB);
  // iter 2
  k_gathersum<<<gS, b256, 0, stream>>>(msgA, a2b, amsg, 0);
  k_gemm<256, MODE_MSG, false><<<gB, 1024, 0, stream>>>(
      amsg, msgA, b2a, b2revb, Wth, inp, nullptr, msgB, cNB);
  // readout
  k_gathersum<<<gS, b256, 0, stream>>>(msgB, a2b, amsg, 0);
  k_gemm<KP_F, MODE_BF16OUT, false><<<gA, 1024, 0, stream>>>(
      fa16, nullptr, nullptr, nullptr, Wto1, nullptr, nullptr, pf, cNA);
  k_gemm<256, MODE_FINAL, false><<<gA, 1024, 0, stream>>>(
      amsg, nullptr, nullptr, nullptr, Wto2, pf, b_o, ah, cNA);
  k_meanpool<<<6000, b256, 0, stream>>>(ah, out);
}